// Round 15
// baseline (238.064 us; speedup 1.0000x reference)
//
#include <hip/hip_runtime.h>
#include <math.h>

#define SEQ    4096
#define DMODEL 1024
#define NHEAD  16
#define DHEAD  64
#define KVQ    1024           // keys per attention block (split-KV x4)

typedef __bf16 bf16;
typedef bf16  bf16x4 __attribute__((ext_vector_type(4)));
typedef bf16  bf16x8 __attribute__((ext_vector_type(8)));
typedef float f32x4  __attribute__((ext_vector_type(4)));
typedef float f32x16 __attribute__((ext_vector_type(16)));
typedef unsigned int u32;

// involutive 16B-chunk swizzles
#define SWZ(r)  ((((r) >> 2) ^ (r)) & 7)                    // GEMM
#define SWZ3(r) (((r) ^ ((r) >> 2) ^ ((r) >> 3)) & 7)       // attn (K tile)

#define SCQ 0.18033688f       // 0.125 * log2(e), folded into Q projection

__device__ __forceinline__ void gll16(const void* g, void* l) {
    __builtin_amdgcn_global_load_lds(
        (const __attribute__((address_space(1))) void*)g,
        (__attribute__((address_space(3))) void*)l, 16, 0, 0);
}

__device__ __forceinline__ u32 cvtpk(float lo, float hi) {
    u32 r;
    asm("v_cvt_pk_bf16_f32 %0, %1, %2" : "=v"(r) : "v"(lo), "v"(hi));
    return r;
}
__device__ __forceinline__ void pswap(u32& a, u32& b) {
    asm volatile("v_permlane32_swap_b32 %0, %1" : "+v"(a), "+v"(b));
}

// ---------------------------------------------------------------------------
// fused fp32 -> bf16 convert for all 7 inputs (one launch)
// ---------------------------------------------------------------------------
__global__ __launch_bounds__(256)
void cvt_all(const float* __restrict__ q, const float* __restrict__ k,
             const float* __restrict__ v, const float* __restrict__ Wq,
             const float* __restrict__ Wk, const float* __restrict__ Wv,
             const float* __restrict__ Wfc,
             bf16* __restrict__ qb, bf16* __restrict__ kb, bf16* __restrict__ vb,
             bf16* __restrict__ Wqb, bf16* __restrict__ Wkb, bf16* __restrict__ Wvb,
             bf16* __restrict__ Wfcb)
{
    const int b = blockIdx.x;
    const float* s; bf16* d; int base;
    if      (b < 2048) { s = q;   d = qb;   base = b; }
    else if (b < 4096) { s = k;   d = kb;   base = b - 2048; }
    else if (b < 6144) { s = v;   d = vb;   base = b - 4096; }
    else if (b < 6656) { s = Wq;  d = Wqb;  base = b - 6144; }
    else if (b < 7168) { s = Wk;  d = Wkb;  base = b - 6656; }
    else if (b < 7680) { s = Wv;  d = Wvb;  base = b - 7168; }
    else               { s = Wfc; d = Wfcb; base = b - 7680; }
    const int i = (base * 256 + threadIdx.x) * 8;
    float4 a0 = *(const float4*)&s[i];
    float4 a1 = *(const float4*)&s[i + 4];
    bf16x8 o;
    o[0] = (bf16)a0.x; o[1] = (bf16)a0.y; o[2] = (bf16)a0.z; o[3] = (bf16)a0.w;
    o[4] = (bf16)a1.x; o[5] = (bf16)a1.y; o[6] = (bf16)a1.z; o[7] = (bf16)a1.w;
    *(bf16x8*)&d[i] = o;
}

// ---------------------------------------------------------------------------
// bf16 MFMA GEMM body (proven R6/R7).  C[bm..][bn..] = A * B^T, K=1024.
// EPI==0: bf16 row-major (x scale).  EPI==1: fp32 relu(acc)+res.
// EPI==2: bf16 TILED: C as [M/64][N/64][64][64] contiguous tiles (x scale).
// ---------------------------------------------------------------------------
template<int EPI>
__device__ __forceinline__ void gemm_body(
    const bf16* __restrict__ A, const bf16* __restrict__ B,
    bf16* __restrict__ Cb, float* __restrict__ Cf, const float* __restrict__ res,
    int bm, int bn, int N, float scale)
{
    constexpr int K = DMODEL;
    const int tid  = threadIdx.x;
    const int w    = tid >> 6;
    const int lane = tid & 63;
    const int lr   = lane & 15;
    const int lh   = lane >> 4;
    const int wr   = w >> 1;
    const int wc   = w & 1;
    const int lrow = lane >> 3;
    const int lch  = lane & 7;

    __shared__ bf16 As[64 * 64];
    __shared__ bf16 Bs[64 * 64];

    f32x4 acc[2][2] = {};

    for (int k0 = 0; k0 < K; k0 += 64) {
        __syncthreads();
        #pragma unroll
        for (int i = 0; i < 2; ++i) {
            const int r = (w * 2 + i) * 8 + lrow;
            gll16(A + (size_t)(bm + r) * K + k0 + ((lch ^ SWZ(r)) << 3),
                  &As[(w * 2 + i) * 512]);
        }
        #pragma unroll
        for (int i = 0; i < 2; ++i) {
            const int r = (w * 2 + i) * 8 + lrow;
            gll16(B + (size_t)(bn + r) * K + k0 + ((lch ^ SWZ(r)) << 3),
                  &Bs[(w * 2 + i) * 512]);
        }
        asm volatile("s_waitcnt vmcnt(0)" ::: "memory");
        __syncthreads();

        bf16x8 af[2][2], bfr[2][2];
        #pragma unroll
        for (int rt = 0; rt < 2; ++rt)
            #pragma unroll
            for (int s = 0; s < 2; ++s) {
                const int r = wr * 32 + rt * 16 + lr;
                af[rt][s] = *(const bf16x8*)&As[r * 64 + (((s * 4 + lh) ^ SWZ(r)) << 3)];
            }
        #pragma unroll
        for (int ct = 0; ct < 2; ++ct)
            #pragma unroll
            for (int s = 0; s < 2; ++s) {
                const int r = wc * 32 + ct * 16 + lr;
                bfr[ct][s] = *(const bf16x8*)&Bs[r * 64 + (((s * 4 + lh) ^ SWZ(r)) << 3)];
            }
        __builtin_amdgcn_s_setprio(1);
        #pragma unroll
        for (int rt = 0; rt < 2; ++rt)
            #pragma unroll
            for (int ct = 0; ct < 2; ++ct)
                #pragma unroll
                for (int s = 0; s < 2; ++s)
                    acc[rt][ct] = __builtin_amdgcn_mfma_f32_16x16x32_bf16(
                        af[rt][s], bfr[ct][s], acc[rt][ct], 0, 0, 0);
        __builtin_amdgcn_s_setprio(0);
    }

    #pragma unroll
    for (int rt = 0; rt < 2; ++rt)
        #pragma unroll
        for (int ct = 0; ct < 2; ++ct)
            #pragma unroll
            for (int r = 0; r < 4; ++r) {
                const int m = bm + wr * 32 + rt * 16 + lh * 4 + r;
                const int n = bn + wc * 32 + ct * 16 + lr;
                const float vv = acc[rt][ct][r] * scale;
                if (EPI == 0) {
                    Cb[(size_t)m * N + n] = (bf16)vv;
                } else if (EPI == 2) {
                    Cb[(((size_t)(m >> 6) * (size_t)(N >> 6) + (size_t)(n >> 6)) << 12)
                       + ((m & 63) << 6) + (n & 63)] = (bf16)vv;
                } else {
                    Cf[(size_t)m * N + n] =
                        fmaxf(vv, 0.f) + res[(size_t)m * N + n];
                }
            }
}

// QKV projections in one launch. z==0: Q (scaled by SCQ). z==1: K.
// z==2: V with swapped operands -> V^T written as 64x64 [d][key] tiles.
__global__ __launch_bounds__(256)
void gemm_qkv(const bf16* __restrict__ qb, const bf16* __restrict__ kb,
              const bf16* __restrict__ vb, const bf16* __restrict__ Wqb,
              const bf16* __restrict__ Wkb, const bf16* __restrict__ Wvb,
              bf16* __restrict__ Pq, bf16* __restrict__ Pk, bf16* __restrict__ Pvt)
{
    if (blockIdx.z == 0)
        gemm_body<0>(qb, Wqb, Pq, nullptr, nullptr,
                     blockIdx.y * 64, blockIdx.x * 64, DMODEL, SCQ);
    else if (blockIdx.z == 1)
        gemm_body<0>(kb, Wkb, Pk, nullptr, nullptr,
                     blockIdx.y * 64, blockIdx.x * 64, DMODEL, 1.0f);
    else
        gemm_body<2>(Wvb, vb, Pvt, nullptr, nullptr,
                     blockIdx.x * 64, blockIdx.y * 64, SEQ, 1.0f);
}

__global__ __launch_bounds__(256)
void gemm_fc(const bf16* __restrict__ AO, const bf16* __restrict__ Wfcb,
             float* __restrict__ out, const float* __restrict__ res)
{
    gemm_body<1>(AO, Wfcb, nullptr, out, res,
                 blockIdx.y * 64, blockIdx.x * 64, DMODEL, 1.0f);
}

// ---------------------------------------------------------------------------
// MFMA flash attention — R12 inner loop, V^T read DIRECTLY from tiled global
// into B-frag registers (8 KB tile is L1/L2-resident; LDS staging was pure
// overhead). LDS = Ks double-buffer only (16 KB). Chunk tail = vmcnt(0)
// (K gll16 only, long since landed) + barrier.
// ---------------------------------------------------------------------------
__global__ __launch_bounds__(256, 4)
void attn_mfma(const bf16* __restrict__ Q, const bf16* __restrict__ K,
               const bf16* __restrict__ Vt_g,
               bf16* __restrict__ Oabc, bf16* Od, float* __restrict__ Lbase)
{
    // bijective XCD swizzle over 2048 blocks: 256 logical per XCD (= 2 heads)
    const int wg   = blockIdx.x;
    const int lgc  = (wg & 7) * 256 + (wg >> 3);
    const int h    = lgc >> 7;
    const int qt   = (lgc >> 5) & 3;
    const int q0   = (lgc & 31) * 128;
    const int c0   = qt * KVQ;

    bf16*  Op = (qt < 3) ? (Oabc + (size_t)qt * (SEQ * DMODEL)) : Od;
    float* Lp = Lbase + qt * (NHEAD * SEQ);

    const int tid  = threadIdx.x;
    const int w    = tid >> 6;
    const int lane = tid & 63;
    const int lo5  = lane & 31;
    const int hi   = lane >> 5;
    const int lrow = lane >> 3;
    const int lch  = lane & 7;

    __shared__ bf16 Ks[2][64 * 64];     // 16 KB total

    const bf16* qrow = Q + (size_t)(q0 + w * 32 + lo5) * DMODEL + h * 64;
    bf16x8 qf[4];
    #pragma unroll
    for (int s = 0; s < 4; ++s)
        qf[s] = *(const bf16x8*)&qrow[s * 16 + hi * 8];

    f32x16 acc0 = {}, acc1 = {};
    float lsum = 0.f;

    const bf16* Vth = Vt_g + ((size_t)h * (SEQ / 64) << 12);

    // per-lane V^T element offsets within a tile (chunk-invariant)
    const int vr0 = lo5 * 64;           // row lo5
    const int vr1 = (32 + lo5) * 64;    // row 32+lo5

    // ---- prologue: stage K chunk 0 of this quarter into buffer 0
    #pragma unroll
    for (int i = 0; i < 2; ++i) {
        const int r = (w * 2 + i) * 8 + lrow;
        gll16(K + (size_t)(c0 + r) * DMODEL + h * 64 + ((lch ^ SWZ3(r)) << 3),
              &Ks[0][(w * 2 + i) * 512]);
    }
    asm volatile("s_waitcnt vmcnt(0)" ::: "memory");
    __syncthreads();

#define BODY(CUR, CN)                                                          \
    {                                                                          \
        const int cn = c0 + (((CN) - c0) & (KVQ - 1));                         \
        /* prefetch next K chunk into the other buffer */                      \
        _Pragma("unroll")                                                      \
        for (int i = 0; i < 2; ++i) {                                          \
            const int r = (w * 2 + i) * 8 + lrow;                              \
            gll16(K + (size_t)(cn + r) * DMODEL + h * 64 + ((lch ^ SWZ3(r)) << 3), \
                  &Ks[(CUR) ^ 1][(w * 2 + i) * 512]);                          \
        }                                                                      \
        /* current chunk's V^T tile (direct-from-global B-frags) */            \
        const bf16* vt = Vth + (((size_t)(((CN) - 64) >> 6)) << 12);           \
        const bf16* Kc = Ks[CUR];                                              \
        _Pragma("unroll")                                                      \
        for (int kh = 0; kh < 2; ++kh) {                                       \
            const int rr = kh * 32 + lo5;                                      \
            /* issue V loads early: consumed ~200+ cyc later in PV */          \
            bf16x8 va0 = *(const bf16x8*)&vt[vr0 + (kh * 4 + hi) * 8];         \
            bf16x8 vb0 = *(const bf16x8*)&vt[vr0 + (kh * 4 + 2 + hi) * 8];     \
            bf16x8 va1 = *(const bf16x8*)&vt[vr1 + (kh * 4 + hi) * 8];         \
            bf16x8 vb1 = *(const bf16x8*)&vt[vr1 + (kh * 4 + 2 + hi) * 8];     \
            f32x16 st = {};                                                    \
            __builtin_amdgcn_s_setprio(1);                                     \
            _Pragma("unroll")                                                  \
            for (int s = 0; s < 4; ++s) {                                      \
                bf16x8 kf = *(const bf16x8*)&Kc[rr * 64 + (((s * 2 + hi) ^ SWZ3(rr)) << 3)]; \
                st = __builtin_amdgcn_mfma_f32_32x32x16_bf16(kf, qf[s], st, 0, 0, 0); \
            }                                                                  \
            __builtin_amdgcn_s_setprio(0);                                     \
            _Pragma("unroll")                                                  \
            for (int r = 0; r < 16; ++r)                                       \
                st[r] = __builtin_amdgcn_exp2f(st[r]);                         \
            lsum += (((st[0] + st[1]) + (st[2] + st[3]))                       \
                   + ((st[4] + st[5]) + (st[6] + st[7])))                      \
                  + (((st[8] + st[9]) + (st[10] + st[11]))                     \
                   + ((st[12] + st[13]) + (st[14] + st[15])));                 \
            _Pragma("unroll")                                                  \
            for (int kk = 0; kk < 2; ++kk) {                                   \
                const int b = kk * 8;                                          \
                u32 A0 = cvtpk(st[b + 0], st[b + 1]);                          \
                u32 C0 = cvtpk(st[b + 2], st[b + 3]);                          \
                u32 B0 = cvtpk(st[b + 4], st[b + 5]);                          \
                u32 D0 = cvtpk(st[b + 6], st[b + 7]);                          \
                pswap(A0, B0);                                                 \
                pswap(C0, D0);                                                 \
                union { u32 wd[4]; bf16x8 v; } fr;                             \
                fr.wd[0] = A0; fr.wd[1] = C0; fr.wd[2] = B0; fr.wd[3] = D0;    \
                bf16x8 vf0 = kk ? vb0 : va0;                                   \
                bf16x8 vf1 = kk ? vb1 : va1;                                   \
                __builtin_amdgcn_s_setprio(1);                                 \
                acc0 = __builtin_amdgcn_mfma_f32_32x32x16_bf16(vf0, fr.v, acc0, 0, 0, 0); \
                acc1 = __builtin_amdgcn_mfma_f32_32x32x16_bf16(vf1, fr.v, acc1, 0, 0, 0); \
                __builtin_amdgcn_s_setprio(0);                                 \
            }                                                                  \
        }                                                                      \
        asm volatile("s_waitcnt vmcnt(0)" ::: "memory");                       \
        __syncthreads();                                                       \
    }

    for (int c = c0; c < c0 + KVQ; c += 128) {
        BODY(0, c + 64)
        BODY(1, c + 128)
    }
#undef BODY

    // per-row partial sum (this quarter's 1024 keys)
    float lt = lsum;
    lt += __shfl_xor(lt, 32);
    Lp[h * SEQ + q0 + w * 32 + lo5] = lt;

    // un-normalized O^T partial -> bf16 (R12 direct epilogue)
    bf16* orow = Op + (size_t)(q0 + w * 32 + lo5) * DMODEL + h * 64;
    #pragma unroll
    for (int g = 0; g < 4; ++g) {
        bf16x4 o4;
        o4[0] = (bf16)acc0[g * 4 + 0];
        o4[1] = (bf16)acc0[g * 4 + 1];
        o4[2] = (bf16)acc0[g * 4 + 2];
        o4[3] = (bf16)acc0[g * 4 + 3];
        *(bf16x4*)&orow[g * 8 + 4 * hi] = o4;
        bf16x4 o5;
        o5[0] = (bf16)acc1[g * 4 + 0];
        o5[1] = (bf16)acc1[g * 4 + 1];
        o5[2] = (bf16)acc1[g * 4 + 2];
        o5[3] = (bf16)acc1[g * 4 + 3];
        *(bf16x4*)&orow[32 + g * 8 + 4 * hi] = o5;
    }
}

// ---------------------------------------------------------------------------
// combine: AO = (Oa + Ob + Oc + Od) / (La + Lb + Lc + Ld)
// AO aliases Od (read-before-write per element, same thread).
// ---------------------------------------------------------------------------
__global__ __launch_bounds__(256)
void combine(const bf16* __restrict__ Oabc, const bf16* Od,
             const float* __restrict__ Lbase, bf16* AO)
{
    const int EM  = SEQ * DMODEL;
    const int e   = (blockIdx.x * 256 + threadIdx.x) * 8;
    const int row = e >> 10;
    const int hh  = (e >> 6) & 15;
    const int li  = hh * SEQ + row;
    const int HS  = NHEAD * SEQ;
    const float inv = 1.0f / (Lbase[li] + Lbase[HS + li]
                            + Lbase[2 * HS + li] + Lbase[3 * HS + li]);
    bf16x8 a = *(const bf16x8*)&Oabc[e];
    bf16x8 b = *(const bf16x8*)&Oabc[EM + e];
    bf16x8 c = *(const bf16x8*)&Oabc[2 * (size_t)EM + e];
    bf16x8 d = *(const bf16x8*)&Od[e];
    bf16x8 o;
    #pragma unroll
    for (int i = 0; i < 8; ++i)
        o[i] = (bf16)((((float)a[i] + (float)b[i]) + ((float)c[i] + (float)d[i])) * inv);
    *(bf16x8*)&AO[e] = o;
}

// ---------------------------------------------------------------------------
extern "C" void kernel_launch(void* const* d_in, const int* in_sizes, int n_in,
                              void* d_out, int out_size, void* d_ws, size_t ws_size,
                              hipStream_t stream)
{
    const float* q   = (const float*)d_in[0];
    const float* k   = (const float*)d_in[1];
    const float* v   = (const float*)d_in[2];
    const float* Wq  = (const float*)d_in[3];
    const float* Wk  = (const float*)d_in[4];
    const float* Wv  = (const float*)d_in[5];
    const float* Wfc = (const float*)d_in[6];
    float* out = (float*)d_out;

    const int EM = SEQ * DMODEL;      // 4M
    const int WM = DMODEL * DMODEL;   // 1M

    // layout (64 MB total): Wfcb | qb kb vb | Wqb Wkb Wvb | Pq Pk Pvt | AO
    bf16* Wfcb = (bf16*)d_ws;
    bf16* qb   = Wfcb + WM;
    bf16* kb   = qb + EM;
    bf16* vb   = kb + EM;
    bf16* Wqb  = vb + EM;
    bf16* Wkb  = Wqb + WM;
    bf16* Wvb  = Wkb + WM;
    bf16* Pq   = Wvb + WM;
    bf16* Pk   = Pq + EM;
    bf16* Pvt  = Pk + EM;             // V^T tiled: [h][kv-tile][64 d][64 key]
    bf16* AO   = Pvt + EM;

    // overlays (valid after gemm_qkv completes):
    bf16*  Oabc = qb;                 // quarters 0-2: qb, kb, vb (contiguous)
    bf16*  Od   = AO;                 // quarter 3 partial aliases AO
    float* Lbase = (float*)Wqb;       // 4 x NHEAD*SEQ fp32 = 1 MB (Wqb retired)

    cvt_all<<<8192, 256, 0, stream>>>(q, k, v, Wq, Wk, Wv, Wfc,
                                      qb, kb, vb, Wqb, Wkb, Wvb, Wfcb);

    gemm_qkv<<<dim3(DMODEL / 64, SEQ / 64, 3), 256, 0, stream>>>(
        qb, kb, vb, Wqb, Wkb, Wvb, Pq, Pk, Pvt);

    attn_mfma<<<2048, 256, 0, stream>>>(Pq, Pk, Pvt, Oabc, Od, Lbase);

    combine<<<EM / 2048, 256, 0, stream>>>(Oabc, Od, Lbase, AO);

    gemm_fc<<<dim3(DMODEL / 64, SEQ / 64), 256, 0, stream>>>(AO, Wfcb, out, q);
}

// Round 16
// 178.105 us; speedup vs baseline: 1.3367x; 1.3367x over previous
//
#include <hip/hip_runtime.h>
#include <math.h>

#define SEQ    4096
#define DMODEL 1024
#define NHEAD  16
#define DHEAD  64
#define KVQ    1024           // keys per attention block (split-KV x4)

typedef __bf16 bf16;
typedef bf16  bf16x4 __attribute__((ext_vector_type(4)));
typedef bf16  bf16x8 __attribute__((ext_vector_type(8)));
typedef float f32x4  __attribute__((ext_vector_type(4)));
typedef float f32x16 __attribute__((ext_vector_type(16)));
typedef unsigned int u32;

// involutive 16B-chunk swizzles
#define SWZ(r)  ((((r) >> 2) ^ (r)) & 7)                    // GEMM
#define SWZ3(r) (((r) ^ ((r) >> 2) ^ ((r) >> 3)) & 7)       // attn

#define SCQ 0.18033688f       // 0.125 * log2(e), folded into Q projection

__device__ __forceinline__ void gll16(const void* g, void* l) {
    __builtin_amdgcn_global_load_lds(
        (const __attribute__((address_space(1))) void*)g,
        (__attribute__((address_space(3))) void*)l, 16, 0, 0);
}

__device__ __forceinline__ u32 cvtpk(float lo, float hi) {
    u32 r;
    asm("v_cvt_pk_bf16_f32 %0, %1, %2" : "=v"(r) : "v"(lo), "v"(hi));
    return r;
}
__device__ __forceinline__ void pswap(u32& a, u32& b) {
    asm volatile("v_permlane32_swap_b32 %0, %1" : "+v"(a), "+v"(b));
}

// ---------------------------------------------------------------------------
// fused fp32 -> bf16 convert for all 7 inputs (one launch)
// ---------------------------------------------------------------------------
__global__ __launch_bounds__(256)
void cvt_all(const float* __restrict__ q, const float* __restrict__ k,
             const float* __restrict__ v, const float* __restrict__ Wq,
             const float* __restrict__ Wk, const float* __restrict__ Wv,
             const float* __restrict__ Wfc,
             bf16* __restrict__ qb, bf16* __restrict__ kb, bf16* __restrict__ vb,
             bf16* __restrict__ Wqb, bf16* __restrict__ Wkb, bf16* __restrict__ Wvb,
             bf16* __restrict__ Wfcb)
{
    const int b = blockIdx.x;
    const float* s; bf16* d; int base;
    if      (b < 2048) { s = q;   d = qb;   base = b; }
    else if (b < 4096) { s = k;   d = kb;   base = b - 2048; }
    else if (b < 6144) { s = v;   d = vb;   base = b - 4096; }
    else if (b < 6656) { s = Wq;  d = Wqb;  base = b - 6144; }
    else if (b < 7168) { s = Wk;  d = Wkb;  base = b - 6656; }
    else if (b < 7680) { s = Wv;  d = Wvb;  base = b - 7168; }
    else               { s = Wfc; d = Wfcb; base = b - 7680; }
    const int i = (base * 256 + threadIdx.x) * 8;
    float4 a0 = *(const float4*)&s[i];
    float4 a1 = *(const float4*)&s[i + 4];
    bf16x8 o;
    o[0] = (bf16)a0.x; o[1] = (bf16)a0.y; o[2] = (bf16)a0.z; o[3] = (bf16)a0.w;
    o[4] = (bf16)a1.x; o[5] = (bf16)a1.y; o[6] = (bf16)a1.z; o[7] = (bf16)a1.w;
    *(bf16x8*)&d[i] = o;
}

// ---------------------------------------------------------------------------
// bf16 MFMA GEMM body (proven R6/R7).  C[bm..][bn..] = A * B^T, K=1024.
// EPI==0: bf16 row-major (x scale).  EPI==1: fp32 relu(acc)+res.
// EPI==2: bf16 TILED: C as [M/64][N/64][64][64] contiguous tiles (x scale).
// ---------------------------------------------------------------------------
template<int EPI>
__device__ __forceinline__ void gemm_body(
    const bf16* __restrict__ A, const bf16* __restrict__ B,
    bf16* __restrict__ Cb, float* __restrict__ Cf, const float* __restrict__ res,
    int bm, int bn, int N, float scale)
{
    constexpr int K = DMODEL;
    const int tid  = threadIdx.x;
    const int w    = tid >> 6;
    const int lane = tid & 63;
    const int lr   = lane & 15;
    const int lh   = lane >> 4;
    const int wr   = w >> 1;
    const int wc   = w & 1;
    const int lrow = lane >> 3;
    const int lch  = lane & 7;

    __shared__ bf16 As[64 * 64];
    __shared__ bf16 Bs[64 * 64];

    f32x4 acc[2][2] = {};

    for (int k0 = 0; k0 < K; k0 += 64) {
        __syncthreads();
        #pragma unroll
        for (int i = 0; i < 2; ++i) {
            const int r = (w * 2 + i) * 8 + lrow;
            gll16(A + (size_t)(bm + r) * K + k0 + ((lch ^ SWZ(r)) << 3),
                  &As[(w * 2 + i) * 512]);
        }
        #pragma unroll
        for (int i = 0; i < 2; ++i) {
            const int r = (w * 2 + i) * 8 + lrow;
            gll16(B + (size_t)(bn + r) * K + k0 + ((lch ^ SWZ(r)) << 3),
                  &Bs[(w * 2 + i) * 512]);
        }
        asm volatile("s_waitcnt vmcnt(0)" ::: "memory");
        __syncthreads();

        bf16x8 af[2][2], bfr[2][2];
        #pragma unroll
        for (int rt = 0; rt < 2; ++rt)
            #pragma unroll
            for (int s = 0; s < 2; ++s) {
                const int r = wr * 32 + rt * 16 + lr;
                af[rt][s] = *(const bf16x8*)&As[r * 64 + (((s * 4 + lh) ^ SWZ(r)) << 3)];
            }
        #pragma unroll
        for (int ct = 0; ct < 2; ++ct)
            #pragma unroll
            for (int s = 0; s < 2; ++s) {
                const int r = wc * 32 + ct * 16 + lr;
                bfr[ct][s] = *(const bf16x8*)&Bs[r * 64 + (((s * 4 + lh) ^ SWZ(r)) << 3)];
            }
        __builtin_amdgcn_s_setprio(1);
        #pragma unroll
        for (int rt = 0; rt < 2; ++rt)
            #pragma unroll
            for (int ct = 0; ct < 2; ++ct)
                #pragma unroll
                for (int s = 0; s < 2; ++s)
                    acc[rt][ct] = __builtin_amdgcn_mfma_f32_16x16x32_bf16(
                        af[rt][s], bfr[ct][s], acc[rt][ct], 0, 0, 0);
        __builtin_amdgcn_s_setprio(0);
    }

    #pragma unroll
    for (int rt = 0; rt < 2; ++rt)
        #pragma unroll
        for (int ct = 0; ct < 2; ++ct)
            #pragma unroll
            for (int r = 0; r < 4; ++r) {
                const int m = bm + wr * 32 + rt * 16 + lh * 4 + r;
                const int n = bn + wc * 32 + ct * 16 + lr;
                const float vv = acc[rt][ct][r] * scale;
                if (EPI == 0) {
                    Cb[(size_t)m * N + n] = (bf16)vv;
                } else if (EPI == 2) {
                    Cb[(((size_t)(m >> 6) * (size_t)(N >> 6) + (size_t)(n >> 6)) << 12)
                       + ((m & 63) << 6) + (n & 63)] = (bf16)vv;
                } else {
                    Cf[(size_t)m * N + n] =
                        fmaxf(vv, 0.f) + res[(size_t)m * N + n];
                }
            }
}

// QKV projections in one launch. z==0: Q (scaled by SCQ). z==1: K.
// z==2: V with swapped operands -> V^T written as 64x64 [d][key] tiles.
__global__ __launch_bounds__(256)
void gemm_qkv(const bf16* __restrict__ qb, const bf16* __restrict__ kb,
              const bf16* __restrict__ vb, const bf16* __restrict__ Wqb,
              const bf16* __restrict__ Wkb, const bf16* __restrict__ Wvb,
              bf16* __restrict__ Pq, bf16* __restrict__ Pk, bf16* __restrict__ Pvt)
{
    if (blockIdx.z == 0)
        gemm_body<0>(qb, Wqb, Pq, nullptr, nullptr,
                     blockIdx.y * 64, blockIdx.x * 64, DMODEL, SCQ);
    else if (blockIdx.z == 1)
        gemm_body<0>(kb, Wkb, Pk, nullptr, nullptr,
                     blockIdx.y * 64, blockIdx.x * 64, DMODEL, 1.0f);
    else
        gemm_body<2>(Wvb, vb, Pvt, nullptr, nullptr,
                     blockIdx.x * 64, blockIdx.y * 64, SEQ, 1.0f);
}

__global__ __launch_bounds__(256)
void gemm_fc(const bf16* __restrict__ AO, const bf16* __restrict__ Wfcb,
             float* __restrict__ out, const float* __restrict__ res)
{
    gemm_body<1>(AO, Wfcb, nullptr, out, res,
                 blockIdx.y * 64, blockIdx.x * 64, DMODEL, 1.0f);
}

// ---------------------------------------------------------------------------
// MFMA flash attention — R12 (measured best: attn 104.0 us).
// Swapped-QK^T (32x32x16), in-register softmax (one S-half live at a time),
// K via global_load_lds, V^T via tiled-global vector load -> swizzled LDS,
// split-KV x4, XCD swizzle, scale folded into Q projection.
// ---------------------------------------------------------------------------
__global__ __launch_bounds__(256, 4)
void attn_mfma(const bf16* __restrict__ Q, const bf16* __restrict__ K,
               const bf16* __restrict__ Vt_g,
               bf16* __restrict__ Oabc, bf16* Od, float* __restrict__ Lbase)
{
    // bijective XCD swizzle over 2048 blocks: 256 logical per XCD (= 2 heads)
    const int wg   = blockIdx.x;
    const int lgc  = (wg & 7) * 256 + (wg >> 3);
    const int h    = lgc >> 7;
    const int qt   = (lgc >> 5) & 3;
    const int q0   = (lgc & 31) * 128;
    const int c0   = qt * KVQ;

    bf16*  Op = (qt < 3) ? (Oabc + (size_t)qt * (SEQ * DMODEL)) : Od;
    float* Lp = Lbase + qt * (NHEAD * SEQ);

    const int tid  = threadIdx.x;
    const int w    = tid >> 6;
    const int lane = tid & 63;
    const int lo5  = lane & 31;
    const int hi   = lane >> 5;
    const int lrow = lane >> 3;
    const int lch  = lane & 7;

    __shared__ bf16 Ks[2][64 * 64];
    __shared__ bf16 Vt[2][64 * 64];

    const bf16* qrow = Q + (size_t)(q0 + w * 32 + lo5) * DMODEL + h * 64;
    bf16x8 qf[4];
    #pragma unroll
    for (int s = 0; s < 4; ++s)
        qf[s] = *(const bf16x8*)&qrow[s * 16 + hi * 8];

    f32x16 acc0 = {}, acc1 = {};
    float lsum = 0.f;

    // V^T tile geometry: thread -> row d = tid>>2, key chunks (tid&3)*2, +1
    const int vd  = tid >> 2;
    const int vc2 = (tid & 3) * 2;
    const int voff = vd * 64 + vc2 * 8;
    const int vw0 = vd * 64 + (((vc2 + 0) ^ SWZ3(vd)) << 3);
    const int vw1 = vd * 64 + (((vc2 + 1) ^ SWZ3(vd)) << 3);
    const bf16* Vth = Vt_g + ((size_t)h * (SEQ / 64) << 12);

    // ---- prologue: stage first chunk of this quarter into buffer 0
    #pragma unroll
    for (int i = 0; i < 2; ++i) {
        const int r = (w * 2 + i) * 8 + lrow;
        gll16(K + (size_t)(c0 + r) * DMODEL + h * 64 + ((lch ^ SWZ3(r)) << 3),
              &Ks[0][(w * 2 + i) * 512]);
    }
    {
        const bf16* vt = Vth + (((size_t)(c0 >> 6)) << 12);
        bf16x8 u0 = *(const bf16x8*)&vt[voff];
        bf16x8 u1 = *(const bf16x8*)&vt[voff + 8];
        asm volatile("s_waitcnt vmcnt(0)" ::: "memory");
        *(bf16x8*)&Vt[0][vw0] = u0;
        *(bf16x8*)&Vt[0][vw1] = u1;
    }
    __syncthreads();

#define BODY(CUR, CN)                                                          \
    {                                                                          \
        const int cn = c0 + (((CN) - c0) & (KVQ - 1));                         \
        _Pragma("unroll")                                                      \
        for (int i = 0; i < 2; ++i) {                                          \
            const int r = (w * 2 + i) * 8 + lrow;                              \
            gll16(K + (size_t)(cn + r) * DMODEL + h * 64 + ((lch ^ SWZ3(r)) << 3), \
                  &Ks[(CUR) ^ 1][(w * 2 + i) * 512]);                          \
        }                                                                      \
        const bf16* vt = Vth + (((size_t)(cn >> 6)) << 12);                    \
        bf16x8 u0 = *(const bf16x8*)&vt[voff];                                 \
        bf16x8 u1 = *(const bf16x8*)&vt[voff + 8];                             \
        const bf16* Kc = Ks[CUR];                                              \
        const bf16* Vc = Vt[CUR];                                              \
        _Pragma("unroll")                                                      \
        for (int kh = 0; kh < 2; ++kh) {                                       \
            const int rr = kh * 32 + lo5;                                      \
            f32x16 st = {};                                                    \
            __builtin_amdgcn_s_setprio(1);                                     \
            _Pragma("unroll")                                                  \
            for (int s = 0; s < 4; ++s) {                                      \
                bf16x8 kf = *(const bf16x8*)&Kc[rr * 64 + (((s * 2 + hi) ^ SWZ3(rr)) << 3)]; \
                st = __builtin_amdgcn_mfma_f32_32x32x16_bf16(kf, qf[s], st, 0, 0, 0); \
            }                                                                  \
            __builtin_amdgcn_s_setprio(0);                                     \
            _Pragma("unroll")                                                  \
            for (int r = 0; r < 16; ++r)                                       \
                st[r] = __builtin_amdgcn_exp2f(st[r]);                         \
            lsum += (((st[0] + st[1]) + (st[2] + st[3]))                       \
                   + ((st[4] + st[5]) + (st[6] + st[7])))                      \
                  + (((st[8] + st[9]) + (st[10] + st[11]))                     \
                   + ((st[12] + st[13]) + (st[14] + st[15])));                 \
            _Pragma("unroll")                                                  \
            for (int kk = 0; kk < 2; ++kk) {                                   \
                const int ks = kh * 2 + kk;                                    \
                const int b = kk * 8;                                          \
                u32 A0 = cvtpk(st[b + 0], st[b + 1]);                          \
                u32 C0 = cvtpk(st[b + 2], st[b + 3]);                          \
                u32 B0 = cvtpk(st[b + 4], st[b + 5]);                          \
                u32 D0 = cvtpk(st[b + 6], st[b + 7]);                          \
                pswap(A0, B0);                                                 \
                pswap(C0, D0);                                                 \
                union { u32 wd[4]; bf16x8 v; } fr;                             \
                fr.wd[0] = A0; fr.wd[1] = C0; fr.wd[2] = B0; fr.wd[3] = D0;    \
                bf16x8 vf0 = *(const bf16x8*)&Vc[lo5 * 64 + (((ks * 2 + hi) ^ SWZ3(lo5)) << 3)]; \
                bf16x8 vf1 = *(const bf16x8*)&Vc[(32 + lo5) * 64 + (((ks * 2 + hi) ^ SWZ3(32 + lo5)) << 3)]; \
                __builtin_amdgcn_s_setprio(1);                                 \
                acc0 = __builtin_amdgcn_mfma_f32_32x32x16_bf16(vf0, fr.v, acc0, 0, 0, 0); \
                acc1 = __builtin_amdgcn_mfma_f32_32x32x16_bf16(vf1, fr.v, acc1, 0, 0, 0); \
                __builtin_amdgcn_s_setprio(0);                                 \
            }                                                                  \
        }                                                                      \
        asm volatile("s_waitcnt vmcnt(0)" ::: "memory");                       \
        {                                                                      \
            bf16* Vn = Vt[(CUR) ^ 1];                                          \
            *(bf16x8*)&Vn[vw0] = u0;                                           \
            *(bf16x8*)&Vn[vw1] = u1;                                           \
        }                                                                      \
        __syncthreads();                                                       \
    }

    for (int c = c0; c < c0 + KVQ; c += 128) {
        BODY(0, c + 64)
        BODY(1, c + 128)
    }
#undef BODY

    // per-row partial sum (this quarter's 1024 keys)
    float lt = lsum;
    lt += __shfl_xor(lt, 32);
    Lp[h * SEQ + q0 + w * 32 + lo5] = lt;

    // un-normalized O^T partial -> bf16
    bf16* orow = Op + (size_t)(q0 + w * 32 + lo5) * DMODEL + h * 64;
    #pragma unroll
    for (int g = 0; g < 4; ++g) {
        bf16x4 o4;
        o4[0] = (bf16)acc0[g * 4 + 0];
        o4[1] = (bf16)acc0[g * 4 + 1];
        o4[2] = (bf16)acc0[g * 4 + 2];
        o4[3] = (bf16)acc0[g * 4 + 3];
        *(bf16x4*)&orow[g * 8 + 4 * hi] = o4;
        bf16x4 o5;
        o5[0] = (bf16)acc1[g * 4 + 0];
        o5[1] = (bf16)acc1[g * 4 + 1];
        o5[2] = (bf16)acc1[g * 4 + 2];
        o5[3] = (bf16)acc1[g * 4 + 3];
        *(bf16x4*)&orow[32 + g * 8 + 4 * hi] = o5;
    }
}

// ---------------------------------------------------------------------------
// combine: AO = (Oa + Ob + Oc + Od) / (La + Lb + Lc + Ld)
// AO aliases Od (read-before-write per element, same thread).
// ---------------------------------------------------------------------------
__global__ __launch_bounds__(256)
void combine(const bf16* __restrict__ Oabc, const bf16* Od,
             const float* __restrict__ Lbase, bf16* AO)
{
    const int EM  = SEQ * DMODEL;
    const int e   = (blockIdx.x * 256 + threadIdx.x) * 8;
    const int row = e >> 10;
    const int hh  = (e >> 6) & 15;
    const int li  = hh * SEQ + row;
    const int HS  = NHEAD * SEQ;
    const float inv = 1.0f / (Lbase[li] + Lbase[HS + li]
                            + Lbase[2 * HS + li] + Lbase[3 * HS + li]);
    bf16x8 a = *(const bf16x8*)&Oabc[e];
    bf16x8 b = *(const bf16x8*)&Oabc[EM + e];
    bf16x8 c = *(const bf16x8*)&Oabc[2 * (size_t)EM + e];
    bf16x8 d = *(const bf16x8*)&Od[e];
    bf16x8 o;
    #pragma unroll
    for (int i = 0; i < 8; ++i)
        o[i] = (bf16)((((float)a[i] + (float)b[i]) + ((float)c[i] + (float)d[i])) * inv);
    *(bf16x8*)&AO[e] = o;
}

// ---------------------------------------------------------------------------
extern "C" void kernel_launch(void* const* d_in, const int* in_sizes, int n_in,
                              void* d_out, int out_size, void* d_ws, size_t ws_size,
                              hipStream_t stream)
{
    const float* q   = (const float*)d_in[0];
    const float* k   = (const float*)d_in[1];
    const float* v   = (const float*)d_in[2];
    const float* Wq  = (const float*)d_in[3];
    const float* Wk  = (const float*)d_in[4];
    const float* Wv  = (const float*)d_in[5];
    const float* Wfc = (const float*)d_in[6];
    float* out = (float*)d_out;

    const int EM = SEQ * DMODEL;      // 4M
    const int WM = DMODEL * DMODEL;   // 1M

    // layout (64 MB total): Wfcb | qb kb vb | Wqb Wkb Wvb | Pq Pk Pvt | AO
    bf16* Wfcb = (bf16*)d_ws;
    bf16* qb   = Wfcb + WM;
    bf16* kb   = qb + EM;
    bf16* vb   = kb + EM;
    bf16* Wqb  = vb + EM;
    bf16* Wkb  = Wqb + WM;
    bf16* Wvb  = Wkb + WM;
    bf16* Pq   = Wvb + WM;
    bf16* Pk   = Pq + EM;
    bf16* Pvt  = Pk + EM;             // V^T tiled: [h][kv-tile][64 d][64 key]
    bf16* AO   = Pvt + EM;

    // overlays (valid after gemm_qkv completes):
    bf16*  Oabc = qb;                 // quarters 0-2: qb, kb, vb (contiguous)
    bf16*  Od   = AO;                 // quarter 3 partial aliases AO
    float* Lbase = (float*)Wqb;       // 4 x NHEAD*SEQ fp32 = 1 MB (Wqb retired)

    cvt_all<<<8192, 256, 0, stream>>>(q, k, v, Wq, Wk, Wv, Wfc,
                                      qb, kb, vb, Wqb, Wkb, Wvb, Wfcb);

    gemm_qkv<<<dim3(DMODEL / 64, SEQ / 64, 3), 256, 0, stream>>>(
        qb, kb, vb, Wqb, Wkb, Wvb, Pq, Pk, Pvt);

    attn_mfma<<<2048, 256, 0, stream>>>(Pq, Pk, Pvt, Oabc, Od, Lbase);

    combine<<<EM / 2048, 256, 0, stream>>>(Oabc, Od, Lbase, AO);

    gemm_fc<<<dim3(DMODEL / 64, SEQ / 64), 256, 0, stream>>>(AO, Wfcb, out, q);
}

// Round 17
// 176.542 us; speedup vs baseline: 1.3485x; 1.0088x over previous
//
#include <hip/hip_runtime.h>
#include <math.h>

#define SEQ    4096
#define DMODEL 1024
#define NHEAD  16
#define DHEAD  64
#define KVQ    1024           // keys per attention block (split-KV x4)

typedef __bf16 bf16;
typedef bf16  bf16x4 __attribute__((ext_vector_type(4)));
typedef bf16  bf16x8 __attribute__((ext_vector_type(8)));
typedef float f32x4  __attribute__((ext_vector_type(4)));
typedef float f32x16 __attribute__((ext_vector_type(16)));
typedef unsigned int u32;

// involutive 16B-chunk swizzles
#define SWZ(r)  ((((r) >> 2) ^ (r)) & 7)                    // GEMM
#define SWZ3(r) (((r) ^ ((r) >> 2) ^ ((r) >> 3)) & 7)       // attn

#define SCQ 0.18033688f       // 0.125 * log2(e), folded into Q projection

__device__ __forceinline__ void gll16(const void* g, void* l) {
    __builtin_amdgcn_global_load_lds(
        (const __attribute__((address_space(1))) void*)g,
        (__attribute__((address_space(3))) void*)l, 16, 0, 0);
}

__device__ __forceinline__ u32 cvtpk(float lo, float hi) {
    u32 r;
    asm("v_cvt_pk_bf16_f32 %0, %1, %2" : "=v"(r) : "v"(lo), "v"(hi));
    return r;
}
__device__ __forceinline__ void pswap(u32& a, u32& b) {
    asm volatile("v_permlane32_swap_b32 %0, %1" : "+v"(a), "+v"(b));
}

// ---------------------------------------------------------------------------
// fused fp32 -> bf16 convert for all 7 inputs (one launch)
// ---------------------------------------------------------------------------
__global__ __launch_bounds__(256)
void cvt_all(const float* __restrict__ q, const float* __restrict__ k,
             const float* __restrict__ v, const float* __restrict__ Wq,
             const float* __restrict__ Wk, const float* __restrict__ Wv,
             const float* __restrict__ Wfc,
             bf16* __restrict__ qb, bf16* __restrict__ kb, bf16* __restrict__ vb,
             bf16* __restrict__ Wqb, bf16* __restrict__ Wkb, bf16* __restrict__ Wvb,
             bf16* __restrict__ Wfcb)
{
    const int b = blockIdx.x;
    const float* s; bf16* d; int base;
    if      (b < 2048) { s = q;   d = qb;   base = b; }
    else if (b < 4096) { s = k;   d = kb;   base = b - 2048; }
    else if (b < 6144) { s = v;   d = vb;   base = b - 4096; }
    else if (b < 6656) { s = Wq;  d = Wqb;  base = b - 6144; }
    else if (b < 7168) { s = Wk;  d = Wkb;  base = b - 6656; }
    else if (b < 7680) { s = Wv;  d = Wvb;  base = b - 7168; }
    else               { s = Wfc; d = Wfcb; base = b - 7680; }
    const int i = (base * 256 + threadIdx.x) * 8;
    float4 a0 = *(const float4*)&s[i];
    float4 a1 = *(const float4*)&s[i + 4];
    bf16x8 o;
    o[0] = (bf16)a0.x; o[1] = (bf16)a0.y; o[2] = (bf16)a0.z; o[3] = (bf16)a0.w;
    o[4] = (bf16)a1.x; o[5] = (bf16)a1.y; o[6] = (bf16)a1.z; o[7] = (bf16)a1.w;
    *(bf16x8*)&d[i] = o;
}

// ---------------------------------------------------------------------------
// 128x128-tile bf16 MFMA GEMM body (m97 structure): BK=64, 4 waves in 2x2,
// each wave computes 64x64 (4x4 16x16 frags). ~160 VGPR -> 3 waves/SIMD.
// EPI==0: bf16 row-major (x scale).
// EPI==2: bf16 TILED: C as [M/64][N/64][64][64] contiguous tiles (x scale).
// ---------------------------------------------------------------------------
template<int EPI>
__device__ __forceinline__ void gemm_body128(
    const bf16* __restrict__ A, const bf16* __restrict__ B,
    bf16* __restrict__ Cb, int bm, int bn, int N, float scale)
{
    constexpr int K = DMODEL;
    const int tid  = threadIdx.x;
    const int w    = tid >> 6;
    const int lane = tid & 63;
    const int lr   = lane & 15;
    const int lh   = lane >> 4;
    const int wr   = w >> 1;
    const int wc   = w & 1;
    const int lrow = lane >> 3;
    const int lch  = lane & 7;

    __shared__ bf16 As[128 * 64];   // 16 KB
    __shared__ bf16 Bs[128 * 64];   // 16 KB

    f32x4 acc[4][4] = {};

    for (int k0 = 0; k0 < K; k0 += 64) {
        __syncthreads();
        #pragma unroll
        for (int i = 0; i < 4; ++i) {
            const int r = (w * 4 + i) * 8 + lrow;
            gll16(A + (size_t)(bm + r) * K + k0 + ((lch ^ SWZ(r)) << 3),
                  &As[(w * 4 + i) * 512]);
            gll16(B + (size_t)(bn + r) * K + k0 + ((lch ^ SWZ(r)) << 3),
                  &Bs[(w * 4 + i) * 512]);
        }
        asm volatile("s_waitcnt vmcnt(0)" ::: "memory");
        __syncthreads();

        bf16x8 af[4][2], bfr[4][2];
        #pragma unroll
        for (int rt = 0; rt < 4; ++rt)
            #pragma unroll
            for (int s = 0; s < 2; ++s) {
                const int r = wr * 64 + rt * 16 + lr;
                af[rt][s] = *(const bf16x8*)&As[r * 64 + (((s * 4 + lh) ^ SWZ(r)) << 3)];
            }
        #pragma unroll
        for (int ct = 0; ct < 4; ++ct)
            #pragma unroll
            for (int s = 0; s < 2; ++s) {
                const int r = wc * 64 + ct * 16 + lr;
                bfr[ct][s] = *(const bf16x8*)&Bs[r * 64 + (((s * 4 + lh) ^ SWZ(r)) << 3)];
            }
        __builtin_amdgcn_s_setprio(1);
        #pragma unroll
        for (int rt = 0; rt < 4; ++rt)
            #pragma unroll
            for (int ct = 0; ct < 4; ++ct)
                #pragma unroll
                for (int s = 0; s < 2; ++s)
                    acc[rt][ct] = __builtin_amdgcn_mfma_f32_16x16x32_bf16(
                        af[rt][s], bfr[ct][s], acc[rt][ct], 0, 0, 0);
        __builtin_amdgcn_s_setprio(0);
    }

    #pragma unroll
    for (int rt = 0; rt < 4; ++rt)
        #pragma unroll
        for (int ct = 0; ct < 4; ++ct)
            #pragma unroll
            for (int r = 0; r < 4; ++r) {
                const int m = bm + wr * 64 + rt * 16 + lh * 4 + r;
                const int n = bn + wc * 64 + ct * 16 + lr;
                const float vv = acc[rt][ct][r] * scale;
                if (EPI == 0) {
                    Cb[(size_t)m * N + n] = (bf16)vv;
                } else {
                    Cb[(((size_t)(m >> 6) * (size_t)(N >> 6) + (size_t)(n >> 6)) << 12)
                       + ((m & 63) << 6) + (n & 63)] = (bf16)vv;
                }
            }
}

// QKV projections in one launch, 128x128 tiles. z==0: Q (x SCQ). z==1: K.
// z==2: V swapped operands -> V^T written as 64x64 [d][key] tiles.
__global__ __launch_bounds__(256)
void gemm_qkv(const bf16* __restrict__ qb, const bf16* __restrict__ kb,
              const bf16* __restrict__ vb, const bf16* __restrict__ Wqb,
              const bf16* __restrict__ Wkb, const bf16* __restrict__ Wvb,
              bf16* __restrict__ Pq, bf16* __restrict__ Pk, bf16* __restrict__ Pvt)
{
    if (blockIdx.z == 0)
        gemm_body128<0>(qb, Wqb, Pq, blockIdx.y * 128, blockIdx.x * 128, DMODEL, SCQ);
    else if (blockIdx.z == 1)
        gemm_body128<0>(kb, Wkb, Pk, blockIdx.y * 128, blockIdx.x * 128, DMODEL, 1.0f);
    else
        gemm_body128<2>(Wvb, vb, Pvt, blockIdx.x * 128, blockIdx.y * 128, SEQ, 1.0f);
}

// ---------------------------------------------------------------------------
// 64x64-tile GEMM body (proven R6/R7) — kept for the FC layer (N=1024 would
// leave 128^2 tiles at 1 block/CU). EPI==1: fp32 relu(acc)+res.
// ---------------------------------------------------------------------------
__global__ __launch_bounds__(256)
void gemm_fc(const bf16* __restrict__ A, const bf16* __restrict__ B,
             float* __restrict__ Cf, const float* __restrict__ res)
{
    constexpr int K = DMODEL, N = DMODEL;
    const int bm   = blockIdx.y * 64;
    const int bn   = blockIdx.x * 64;
    const int tid  = threadIdx.x;
    const int w    = tid >> 6;
    const int lane = tid & 63;
    const int lr   = lane & 15;
    const int lh   = lane >> 4;
    const int wr   = w >> 1;
    const int wc   = w & 1;
    const int lrow = lane >> 3;
    const int lch  = lane & 7;

    __shared__ bf16 As[64 * 64];
    __shared__ bf16 Bs[64 * 64];

    f32x4 acc[2][2] = {};

    for (int k0 = 0; k0 < K; k0 += 64) {
        __syncthreads();
        #pragma unroll
        for (int i = 0; i < 2; ++i) {
            const int r = (w * 2 + i) * 8 + lrow;
            gll16(A + (size_t)(bm + r) * K + k0 + ((lch ^ SWZ(r)) << 3),
                  &As[(w * 2 + i) * 512]);
        }
        #pragma unroll
        for (int i = 0; i < 2; ++i) {
            const int r = (w * 2 + i) * 8 + lrow;
            gll16(B + (size_t)(bn + r) * K + k0 + ((lch ^ SWZ(r)) << 3),
                  &Bs[(w * 2 + i) * 512]);
        }
        asm volatile("s_waitcnt vmcnt(0)" ::: "memory");
        __syncthreads();

        bf16x8 af[2][2], bfr[2][2];
        #pragma unroll
        for (int rt = 0; rt < 2; ++rt)
            #pragma unroll
            for (int s = 0; s < 2; ++s) {
                const int r = wr * 32 + rt * 16 + lr;
                af[rt][s] = *(const bf16x8*)&As[r * 64 + (((s * 4 + lh) ^ SWZ(r)) << 3)];
            }
        #pragma unroll
        for (int ct = 0; ct < 2; ++ct)
            #pragma unroll
            for (int s = 0; s < 2; ++s) {
                const int r = wc * 32 + ct * 16 + lr;
                bfr[ct][s] = *(const bf16x8*)&Bs[r * 64 + (((s * 4 + lh) ^ SWZ(r)) << 3)];
            }
        __builtin_amdgcn_s_setprio(1);
        #pragma unroll
        for (int rt = 0; rt < 2; ++rt)
            #pragma unroll
            for (int ct = 0; ct < 2; ++ct)
                #pragma unroll
                for (int s = 0; s < 2; ++s)
                    acc[rt][ct] = __builtin_amdgcn_mfma_f32_16x16x32_bf16(
                        af[rt][s], bfr[ct][s], acc[rt][ct], 0, 0, 0);
        __builtin_amdgcn_s_setprio(0);
    }

    #pragma unroll
    for (int rt = 0; rt < 2; ++rt)
        #pragma unroll
        for (int ct = 0; ct < 2; ++ct)
            #pragma unroll
            for (int r = 0; r < 4; ++r) {
                const int m = bm + wr * 32 + rt * 16 + lh * 4 + r;
                const int n = bn + wc * 32 + ct * 16 + lr;
                Cf[(size_t)m * N + n] =
                    fmaxf(acc[rt][ct][r], 0.f) + res[(size_t)m * N + n];
            }
}

// ---------------------------------------------------------------------------
// MFMA flash attention — R12 (measured best: attn ~104 us). UNCHANGED.
// ---------------------------------------------------------------------------
__global__ __launch_bounds__(256, 4)
void attn_mfma(const bf16* __restrict__ Q, const bf16* __restrict__ K,
               const bf16* __restrict__ Vt_g,
               bf16* __restrict__ Oabc, bf16* Od, float* __restrict__ Lbase)
{
    // bijective XCD swizzle over 2048 blocks: 256 logical per XCD (= 2 heads)
    const int wg   = blockIdx.x;
    const int lgc  = (wg & 7) * 256 + (wg >> 3);
    const int h    = lgc >> 7;
    const int qt   = (lgc >> 5) & 3;
    const int q0   = (lgc & 31) * 128;
    const int c0   = qt * KVQ;

    bf16*  Op = (qt < 3) ? (Oabc + (size_t)qt * (SEQ * DMODEL)) : Od;
    float* Lp = Lbase + qt * (NHEAD * SEQ);

    const int tid  = threadIdx.x;
    const int w    = tid >> 6;
    const int lane = tid & 63;
    const int lo5  = lane & 31;
    const int hi   = lane >> 5;
    const int lrow = lane >> 3;
    const int lch  = lane & 7;

    __shared__ bf16 Ks[2][64 * 64];
    __shared__ bf16 Vt[2][64 * 64];

    const bf16* qrow = Q + (size_t)(q0 + w * 32 + lo5) * DMODEL + h * 64;
    bf16x8 qf[4];
    #pragma unroll
    for (int s = 0; s < 4; ++s)
        qf[s] = *(const bf16x8*)&qrow[s * 16 + hi * 8];

    f32x16 acc0 = {}, acc1 = {};
    float lsum = 0.f;

    // V^T tile geometry: thread -> row d = tid>>2, key chunks (tid&3)*2, +1
    const int vd  = tid >> 2;
    const int vc2 = (tid & 3) * 2;
    const int voff = vd * 64 + vc2 * 8;
    const int vw0 = vd * 64 + (((vc2 + 0) ^ SWZ3(vd)) << 3);
    const int vw1 = vd * 64 + (((vc2 + 1) ^ SWZ3(vd)) << 3);
    const bf16* Vth = Vt_g + ((size_t)h * (SEQ / 64) << 12);

    // ---- prologue: stage first chunk of this quarter into buffer 0
    #pragma unroll
    for (int i = 0; i < 2; ++i) {
        const int r = (w * 2 + i) * 8 + lrow;
        gll16(K + (size_t)(c0 + r) * DMODEL + h * 64 + ((lch ^ SWZ3(r)) << 3),
              &Ks[0][(w * 2 + i) * 512]);
    }
    {
        const bf16* vt = Vth + (((size_t)(c0 >> 6)) << 12);
        bf16x8 u0 = *(const bf16x8*)&vt[voff];
        bf16x8 u1 = *(const bf16x8*)&vt[voff + 8];
        asm volatile("s_waitcnt vmcnt(0)" ::: "memory");
        *(bf16x8*)&Vt[0][vw0] = u0;
        *(bf16x8*)&Vt[0][vw1] = u1;
    }
    __syncthreads();

#define BODY(CUR, CN)                                                          \
    {                                                                          \
        const int cn = c0 + (((CN) - c0) & (KVQ - 1));                         \
        _Pragma("unroll")                                                      \
        for (int i = 0; i < 2; ++i) {                                          \
            const int r = (w * 2 + i) * 8 + lrow;                              \
            gll16(K + (size_t)(cn + r) * DMODEL + h * 64 + ((lch ^ SWZ3(r)) << 3), \
                  &Ks[(CUR) ^ 1][(w * 2 + i) * 512]);                          \
        }                                                                      \
        const bf16* vt = Vth + (((size_t)(cn >> 6)) << 12);                    \
        bf16x8 u0 = *(const bf16x8*)&vt[voff];                                 \
        bf16x8 u1 = *(const bf16x8*)&vt[voff + 8];                             \
        const bf16* Kc = Ks[CUR];                                              \
        const bf16* Vc = Vt[CUR];                                              \
        _Pragma("unroll")                                                      \
        for (int kh = 0; kh < 2; ++kh) {                                       \
            const int rr = kh * 32 + lo5;                                      \
            f32x16 st = {};                                                    \
            __builtin_amdgcn_s_setprio(1);                                     \
            _Pragma("unroll")                                                  \
            for (int s = 0; s < 4; ++s) {                                      \
                bf16x8 kf = *(const bf16x8*)&Kc[rr * 64 + (((s * 2 + hi) ^ SWZ3(rr)) << 3)]; \
                st = __builtin_amdgcn_mfma_f32_32x32x16_bf16(kf, qf[s], st, 0, 0, 0); \
            }                                                                  \
            __builtin_amdgcn_s_setprio(0);                                     \
            _Pragma("unroll")                                                  \
            for (int r = 0; r < 16; ++r)                                       \
                st[r] = __builtin_amdgcn_exp2f(st[r]);                         \
            lsum += (((st[0] + st[1]) + (st[2] + st[3]))                       \
                   + ((st[4] + st[5]) + (st[6] + st[7])))                      \
                  + (((st[8] + st[9]) + (st[10] + st[11]))                     \
                   + ((st[12] + st[13]) + (st[14] + st[15])));                 \
            _Pragma("unroll")                                                  \
            for (int kk = 0; kk < 2; ++kk) {                                   \
                const int ks = kh * 2 + kk;                                    \
                const int b = kk * 8;                                          \
                u32 A0 = cvtpk(st[b + 0], st[b + 1]);                          \
                u32 C0 = cvtpk(st[b + 2], st[b + 3]);                          \
                u32 B0 = cvtpk(st[b + 4], st[b + 5]);                          \
                u32 D0 = cvtpk(st[b + 6], st[b + 7]);                          \
                pswap(A0, B0);                                                 \
                pswap(C0, D0);                                                 \
                union { u32 wd[4]; bf16x8 v; } fr;                             \
                fr.wd[0] = A0; fr.wd[1] = C0; fr.wd[2] = B0; fr.wd[3] = D0;    \
                bf16x8 vf0 = *(const bf16x8*)&Vc[lo5 * 64 + (((ks * 2 + hi) ^ SWZ3(lo5)) << 3)]; \
                bf16x8 vf1 = *(const bf16x8*)&Vc[(32 + lo5) * 64 + (((ks * 2 + hi) ^ SWZ3(32 + lo5)) << 3)]; \
                __builtin_amdgcn_s_setprio(1);                                 \
                acc0 = __builtin_amdgcn_mfma_f32_32x32x16_bf16(vf0, fr.v, acc0, 0, 0, 0); \
                acc1 = __builtin_amdgcn_mfma_f32_32x32x16_bf16(vf1, fr.v, acc1, 0, 0, 0); \
                __builtin_amdgcn_s_setprio(0);                                 \
            }                                                                  \
        }                                                                      \
        asm volatile("s_waitcnt vmcnt(0)" ::: "memory");                       \
        {                                                                      \
            bf16* Vn = Vt[(CUR) ^ 1];                                          \
            *(bf16x8*)&Vn[vw0] = u0;                                           \
            *(bf16x8*)&Vn[vw1] = u1;                                           \
        }                                                                      \
        __syncthreads();                                                       \
    }

    for (int c = c0; c < c0 + KVQ; c += 128) {
        BODY(0, c + 64)
        BODY(1, c + 128)
    }
#undef BODY

    // per-row partial sum (this quarter's 1024 keys)
    float lt = lsum;
    lt += __shfl_xor(lt, 32);
    Lp[h * SEQ + q0 + w * 32 + lo5] = lt;

    // un-normalized O^T partial -> bf16
    bf16* orow = Op + (size_t)(q0 + w * 32 + lo5) * DMODEL + h * 64;
    #pragma unroll
    for (int g = 0; g < 4; ++g) {
        bf16x4 o4;
        o4[0] = (bf16)acc0[g * 4 + 0];
        o4[1] = (bf16)acc0[g * 4 + 1];
        o4[2] = (bf16)acc0[g * 4 + 2];
        o4[3] = (bf16)acc0[g * 4 + 3];
        *(bf16x4*)&orow[g * 8 + 4 * hi] = o4;
        bf16x4 o5;
        o5[0] = (bf16)acc1[g * 4 + 0];
        o5[1] = (bf16)acc1[g * 4 + 1];
        o5[2] = (bf16)acc1[g * 4 + 2];
        o5[3] = (bf16)acc1[g * 4 + 3];
        *(bf16x4*)&orow[32 + g * 8 + 4 * hi] = o5;
    }
}

// ---------------------------------------------------------------------------
// combine: AO = (Oa + Ob + Oc + Od) / (La + Lb + Lc + Ld)
// AO aliases Od (read-before-write per element, same thread).
// ---------------------------------------------------------------------------
__global__ __launch_bounds__(256)
void combine(const bf16* __restrict__ Oabc, const bf16* Od,
             const float* __restrict__ Lbase, bf16* AO)
{
    const int EM  = SEQ * DMODEL;
    const int e   = (blockIdx.x * 256 + threadIdx.x) * 8;
    const int row = e >> 10;
    const int hh  = (e >> 6) & 15;
    const int li  = hh * SEQ + row;
    const int HS  = NHEAD * SEQ;
    const float inv = 1.0f / (Lbase[li] + Lbase[HS + li]
                            + Lbase[2 * HS + li] + Lbase[3 * HS + li]);
    bf16x8 a = *(const bf16x8*)&Oabc[e];
    bf16x8 b = *(const bf16x8*)&Oabc[EM + e];
    bf16x8 c = *(const bf16x8*)&Oabc[2 * (size_t)EM + e];
    bf16x8 d = *(const bf16x8*)&Od[e];
    bf16x8 o;
    #pragma unroll
    for (int i = 0; i < 8; ++i)
        o[i] = (bf16)((((float)a[i] + (float)b[i]) + ((float)c[i] + (float)d[i])) * inv);
    *(bf16x8*)&AO[e] = o;
}

// ---------------------------------------------------------------------------
extern "C" void kernel_launch(void* const* d_in, const int* in_sizes, int n_in,
                              void* d_out, int out_size, void* d_ws, size_t ws_size,
                              hipStream_t stream)
{
    const float* q   = (const float*)d_in[0];
    const float* k   = (const float*)d_in[1];
    const float* v   = (const float*)d_in[2];
    const float* Wq  = (const float*)d_in[3];
    const float* Wk  = (const float*)d_in[4];
    const float* Wv  = (const float*)d_in[5];
    const float* Wfc = (const float*)d_in[6];
    float* out = (float*)d_out;

    const int EM = SEQ * DMODEL;      // 4M
    const int WM = DMODEL * DMODEL;   // 1M

    // layout (64 MB total): Wfcb | qb kb vb | Wqb Wkb Wvb | Pq Pk Pvt | AO
    bf16* Wfcb = (bf16*)d_ws;
    bf16* qb   = Wfcb + WM;
    bf16* kb   = qb + EM;
    bf16* vb   = kb + EM;
    bf16* Wqb  = vb + EM;
    bf16* Wkb  = Wqb + WM;
    bf16* Wvb  = Wkb + WM;
    bf16* Pq   = Wvb + WM;
    bf16* Pk   = Pq + EM;
    bf16* Pvt  = Pk + EM;             // V^T tiled: [h][kv-tile][64 d][64 key]
    bf16* AO   = Pvt + EM;

    // overlays (valid after gemm_qkv completes):
    bf16*  Oabc = qb;                 // quarters 0-2: qb, kb, vb (contiguous)
    bf16*  Od   = AO;                 // quarter 3 partial aliases AO
    float* Lbase = (float*)Wqb;       // 4 x NHEAD*SEQ fp32 = 1 MB (Wqb retired)

    cvt_all<<<8192, 256, 0, stream>>>(q, k, v, Wq, Wk, Wv, Wfc,
                                      qb, kb, vb, Wqb, Wkb, Wvb, Wfcb);

    gemm_qkv<<<dim3(DMODEL / 128, SEQ / 128, 3), 256, 0, stream>>>(
        qb, kb, vb, Wqb, Wkb, Wvb, Pq, Pk, Pvt);

    attn_mfma<<<2048, 256, 0, stream>>>(Pq, Pk, Pvt, Oabc, Od, Lbase);

    combine<<<EM / 2048, 256, 0, stream>>>(Oabc, Od, Lbase, AO);

    gemm_fc<<<dim3(DMODEL / 64, SEQ / 64), 256, 0, stream>>>(AO, Wfcb, out, q);
}